// Round 7
// baseline (757.731 us; speedup 1.0000x reference)
//
#include <hip/hip_runtime.h>
#include <cstdio>
#include <cstdint>

#define TOKS 4096
#define DMODEL 1024
#define DFF 4096
#define NEXP 8

typedef __bf16 bf16_8 __attribute__((ext_vector_type(8)));
typedef float f32x4 __attribute__((ext_vector_type(4)));
typedef __attribute__((address_space(1))) const void* gptr_t;
typedef __attribute__((address_space(3))) void* lptr_t;

__device__ __forceinline__ unsigned short f2bf(float f) {
  unsigned int u = __builtin_bit_cast(unsigned int, f);
  u += 0x7FFFu + ((u >> 16) & 1u);
  return (unsigned short)(u >> 16);
}

// ---------------- transpose + cast fp32 [R][C] -> bf16 [C][R], per-expert (blockIdx.y) ----
__global__ __launch_bounds__(256) void transpose_cast_k(const float* __restrict__ in,
                                                        unsigned short* __restrict__ out,
                                                        int R, int C) {
  __shared__ float tile[64][65];
  const float* inm = in + (size_t)blockIdx.y * R * C;
  unsigned short* outm = out + (size_t)blockIdx.y * R * C;
  int tcn = C >> 6;
  int tr = blockIdx.x / tcn, tc = blockIdx.x % tcn;
  int r0 = tr << 6, c0 = tc << 6;
  int tid = threadIdx.x;
  int lr = tid >> 6, lc = tid & 63;
#pragma unroll
  for (int i = 0; i < 16; ++i)
    tile[lr + 4 * i][lc] = inm[(size_t)(r0 + lr + 4 * i) * C + c0 + lc];
  __syncthreads();
#pragma unroll
  for (int i = 0; i < 8; ++i) {
    int row = (tid >> 5) + i * 8;  // out-row (c index) within tile
    int colu = tid & 31;           // uint column (2 bf16)
    float f0 = tile[colu * 2][row];
    float f1 = tile[colu * 2 + 1][row];
    unsigned int u = (unsigned int)f2bf(f0) | ((unsigned int)f2bf(f1) << 16);
    *(unsigned int*)(outm + (size_t)(c0 + row) * R + r0 + colu * 2) = u;
  }
}

// ---------------- cast x fp32 -> bf16 (vectorized) ----------------
__global__ __launch_bounds__(256) void cast_x_k(const float* __restrict__ x,
                                                unsigned short* __restrict__ xb) {
  int i = blockIdx.x * 256 + threadIdx.x;  // exactly TOKS*DMODEL/4 threads
  float4 f = ((const float4*)x)[i];
  ushort4 u;
  u.x = f2bf(f.x); u.y = f2bf(f.y); u.z = f2bf(f.z); u.w = f2bf(f.w);
  ((ushort4*)xb)[i] = u;
}

// ---------------- router: logits -> top2 -> probs -> expert lists ----------------
__global__ __launch_bounds__(256) void router_k(const float* __restrict__ x,
                                                const float* __restrict__ Wr,
                                                const float* __restrict__ br,
                                                int* __restrict__ cnt,
                                                int* __restrict__ list,
                                                float* __restrict__ plist) {
  int t = blockIdx.x * 4 + (threadIdx.x >> 6);
  int lane = threadIdx.x & 63;
  float a[NEXP];
#pragma unroll
  for (int e = 0; e < NEXP; ++e) a[e] = 0.f;
  const float* xr = x + (size_t)t * DMODEL;
  for (int i = lane; i < DMODEL; i += 64) {
    float xv = xr[i];
    const float* wr = Wr + (size_t)i * NEXP;
#pragma unroll
    for (int e = 0; e < NEXP; ++e) a[e] += xv * wr[e];
  }
#pragma unroll
  for (int off = 32; off > 0; off >>= 1) {
#pragma unroll
    for (int e = 0; e < NEXP; ++e) a[e] += __shfl_xor(a[e], off);
  }
  if (lane == 0) {
#pragma unroll
    for (int e = 0; e < NEXP; ++e) a[e] += br[e];
    int i0 = 0; float m0 = a[0];
#pragma unroll
    for (int e = 1; e < NEXP; ++e) if (a[e] > m0) { m0 = a[e]; i0 = e; }
    int i1 = -1; float m1 = -1e30f;
#pragma unroll
    for (int e = 0; e < NEXP; ++e) if (e != i0 && a[e] > m1) { m1 = a[e]; i1 = e; }
    float tt = expf(m1 - m0);
    float p0 = 1.f / (1.f + tt);
    float p1 = 1.f - p0;
    int pos0 = atomicAdd(&cnt[i0], 1);
    list[i0 * TOKS + pos0] = t; plist[i0 * TOKS + pos0] = p0;
    int pos1 = atomicAdd(&cnt[i1], 1);
    list[i1 * TOKS + pos1] = t; plist[i1 * TOKS + pos1] = p1;
  }
}

__global__ void offsets_k(const int* __restrict__ cnt, int* __restrict__ off) {
  if (threadIdx.x == 0) {
    int s = 0;
    for (int e = 0; e < NEXP; ++e) { off[e] = s; s += cnt[e]; }
    off[NEXP] = s;
  }
}

// ---------------- grouped GEMM, m201-template geometry: BM=256, 8 waves (2x4), BK=64 ------
// 2-phase double-buffered pipeline + bijective XCD-chunked swizzle (one expert per XCD).
// MODE 0: BMxBN=256x256, A = xb rows via list [K=1024], B = W1t, out: h=relu(.+b1) bf16
// MODE 1: BMxBN=256x128, A = h compact rows  [K=4096], B = W2t, out: atomicAdd p*(.+b2)
template <int MODE, int BM, int BN>
__global__ __launch_bounds__(512, 2) void moe_gemm_k(
    const unsigned short* __restrict__ Abase, const unsigned short* __restrict__ Bbase,
    const float* __restrict__ bias, const int* __restrict__ cnt, const int* __restrict__ off,
    const int* __restrict__ list, const float* __restrict__ plist,
    unsigned short* __restrict__ Hout, float* __restrict__ Out) {
  constexpr int K  = (MODE == 0) ? DMODEL : DFF;
  constexpr int NN = (MODE == 0) ? DFF : DMODEL;
  constexpr int NT = NN / BN;           // n-tiles
  constexpr int MT = TOKS / BM;         // worst-case m-tiles (=16)
  constexpr int NWG = NEXP * MT * NT;   // total blocks (%8 == 0)
  constexpr int CHUNK = NWG / 8;
  constexpr int WMSZ = BM / 2;          // per-wave M (=128)
  constexpr int WNSZ = BN / 4;          // per-wave N (64 or 32)
  constexpr int FM = WMSZ / 16;         // 8 m-frags
  constexpr int FN = WNSZ / 16;         // 4 or 2 n-frags
  constexpr int RA = BM / 64;           // A staging rounds (512 thr x 16B = 64 rows/round)
  constexpr int RB = BN / 64;           // B staging rounds

  // bijective XCD swizzle: flat dispatch id -> chunked id u, decoded nt-fastest
  const int flat = blockIdx.x + NT * (blockIdx.y + MT * blockIdx.z);
  const int u = (flat & 7) * CHUNK + (flat >> 3);
  const int nt = u % NT;
  const int mt = (u / NT) % MT;
  const int e = u / (NT * MT);

  const int ce = cnt[e];
  const int m0 = mt * BM;
  if (m0 >= ce) return;                 // empty tile (block-uniform) -> cheap exit
  const int rem = ce - m0;              // >= 1
  const int n0 = nt * BN;
  const int oe = off[e];

  __shared__ unsigned short As[2][BM * 64];  // XOR-swizzled 16B slots
  __shared__ unsigned short Bs[2][BN * 64];

  const int tid = threadIdx.x;
  const int lane = tid & 63;
  const int w = tid >> 6;               // 8 waves: wm in [0,2), wn in [0,4)
  const int wm = w >> 2, wn = w & 3;

  const unsigned short* Bm = Bbase + (size_t)e * NN * K;
  // staging: physical 16B slot s = c*512+tid; row = s>>3; logical k-group = (s&7)^(row&7)
  const int g = (tid & 7) ^ ((tid >> 3) & 7);

  size_t a_src[RA], b_src[RB];
#pragma unroll
  for (int c = 0; c < RA; ++c) {
    int row = c * 64 + (tid >> 3);
    int rr = row < rem ? row : 0;       // clamp padding rows to a valid row
    size_t arow;
    if (MODE == 0) arow = (size_t)list[e * TOKS + m0 + rr];
    else           arow = (size_t)(oe + m0 + rr);
    a_src[c] = arow * K + g * 8;
  }
#pragma unroll
  for (int c = 0; c < RB; ++c) {
    int row = c * 64 + (tid >> 3);
    b_src[c] = (size_t)(n0 + row) * K + g * 8;
  }

  f32x4 acc[FM][FN];
#pragma unroll
  for (int i = 0; i < FM; ++i)
#pragma unroll
    for (int j = 0; j < FN; ++j) acc[i][j] = (f32x4){0.f, 0.f, 0.f, 0.f};

  auto STAGE = [&](int buf, int k0) {
#pragma unroll
    for (int c = 0; c < RA; ++c)
      __builtin_amdgcn_global_load_lds((gptr_t)(Abase + a_src[c] + k0),
                                       (lptr_t)&As[buf][(c * 512 + tid) * 8], 16, 0, 0);
#pragma unroll
    for (int c = 0; c < RB; ++c)
      __builtin_amdgcn_global_load_lds((gptr_t)(Bm + b_src[c] + k0),
                                       (lptr_t)&Bs[buf][(c * 512 + tid) * 8], 16, 0, 0);
  };

  auto COMPUTE = [&](int buf) {
#pragma unroll
    for (int kk = 0; kk < 2; ++kk) {
      bf16_8 av[FM], bv[FN];
#pragma unroll
      for (int fm = 0; fm < FM; ++fm) {
        int row = wm * WMSZ + fm * 16 + (lane & 15);
        int slot = row * 8 + ((kk * 4 + (lane >> 4)) ^ (row & 7));
        av[fm] = *(const bf16_8*)&As[buf][slot * 8];
      }
#pragma unroll
      for (int fc = 0; fc < FN; ++fc) {
        int row = wn * WNSZ + fc * 16 + (lane & 15);
        int slot = row * 8 + ((kk * 4 + (lane >> 4)) ^ (row & 7));
        bv[fc] = *(const bf16_8*)&Bs[buf][slot * 8];
      }
#pragma unroll
      for (int fm = 0; fm < FM; ++fm)
#pragma unroll
        for (int fc = 0; fc < FN; ++fc)
          acc[fm][fc] = __builtin_amdgcn_mfma_f32_16x16x32_bf16(av[fm], bv[fc],
                                                                acc[fm][fc], 0, 0, 0);
    }
  };

  constexpr int NSTEP = K / 64;
  STAGE(0, 0);
  __syncthreads();                      // compiler drains vmcnt before barrier
  int cur = 0;
  for (int t = 0; t < NSTEP - 1; ++t) {
    STAGE(cur ^ 1, (t + 1) * 64);       // prefetch next tile (overlaps with compute)
    COMPUTE(cur);
    __syncthreads();                    // vmcnt(0)+barrier: staged buf ready, reads done
    cur ^= 1;
  }
  COMPUTE(cur);                         // last tile, no prefetch

  const float* be = bias + (size_t)e * NN + n0;
  if (MODE == 0) {
#pragma unroll
    for (int fm = 0; fm < FM; ++fm) {
#pragma unroll
      for (int j = 0; j < 4; ++j) {
        int row = wm * WMSZ + fm * 16 + (lane >> 4) * 4 + j;
        if (row < rem) {
          unsigned short* hr = Hout + (size_t)(oe + m0 + row) * DFF + n0;
#pragma unroll
          for (int fc = 0; fc < FN; ++fc) {
            int col = wn * WNSZ + fc * 16 + (lane & 15);
            float v = acc[fm][fc][j] + be[col];
            hr[col] = f2bf(fmaxf(v, 0.f));
          }
        }
      }
    }
  } else {
#pragma unroll
    for (int fm = 0; fm < FM; ++fm) {
#pragma unroll
      for (int j = 0; j < 4; ++j) {
        int row = wm * WMSZ + fm * 16 + (lane >> 4) * 4 + j;
        if (row < rem) {
          int tok = list[e * TOKS + m0 + row];
          float p = plist[e * TOKS + m0 + row];
          float* orow = Out + (size_t)tok * DMODEL + n0;
#pragma unroll
          for (int fc = 0; fc < FN; ++fc) {
            int col = wn * WNSZ + fc * 16 + (lane & 15);
            atomicAdd(&orow[col], p * (acc[fm][fc][j] + be[col]));
          }
        }
      }
    }
  }
}

extern "C" void kernel_launch(void* const* d_in, const int* in_sizes, int n_in,
                              void* d_out, int out_size, void* d_ws, size_t ws_size,
                              hipStream_t stream) {
  const float* x  = (const float*)d_in[0];
  const float* Wr = (const float*)d_in[1];
  const float* br = (const float*)d_in[2];
  const float* W1 = (const float*)d_in[3];
  const float* b1 = (const float*)d_in[4];
  const float* W2 = (const float*)d_in[5];
  const float* b2 = (const float*)d_in[6];
  float* out = (float*)d_out;

  const size_t SZ_W = (size_t)NEXP * DMODEL * DFF;  // 33.5M elems
  char* ws = (char*)d_ws;
  size_t o = 0;
  unsigned short* W1t = (unsigned short*)(ws + o); o += SZ_W * 2;                  // [E][DFF][DMODEL] bf16
  unsigned short* W2t = (unsigned short*)(ws + o); o += SZ_W * 2;                  // [E][DMODEL][DFF] bf16
  unsigned short* xb  = (unsigned short*)(ws + o); o += (size_t)TOKS * DMODEL * 2; // bf16 x
  unsigned short* h   = (unsigned short*)(ws + o); o += (size_t)2 * TOKS * DFF * 2;// bf16 h (8192 slots)
  int*   cnt   = (int*)(ws + o);   o += 256;
  int*   offp  = (int*)(ws + o);   o += 256;
  int*   list  = (int*)(ws + o);   o += (size_t)NEXP * TOKS * 4;
  float* plist = (float*)(ws + o); o += (size_t)NEXP * TOKS * 4;
  if (o > ws_size) {
    fprintf(stderr, "kernel_launch: ws too small: need %zu have %zu\n", o, ws_size);
    hipMemsetAsync(d_out, 0, (size_t)out_size * 4, stream);
    return;
  }

  hipMemsetAsync(cnt, 0, 256, stream);
  hipMemsetAsync(d_out, 0, (size_t)out_size * 4, stream);

  transpose_cast_k<<<dim3((DMODEL / 64) * (DFF / 64), NEXP), 256, 0, stream>>>(W1, W1t, DMODEL, DFF);
  transpose_cast_k<<<dim3((DFF / 64) * (DMODEL / 64), NEXP), 256, 0, stream>>>(W2, W2t, DFF, DMODEL);
  cast_x_k<<<TOKS * DMODEL / 4 / 256, 256, 0, stream>>>(x, xb);
  router_k<<<TOKS / 4, 256, 0, stream>>>(x, Wr, br, cnt, list, plist);
  offsets_k<<<1, 64, 0, stream>>>(cnt, offp);
  moe_gemm_k<0, 256, 256><<<dim3(DFF / 256, TOKS / 256, NEXP), 512, 0, stream>>>(
      xb, W1t, b1, cnt, offp, list, plist, h, nullptr);
  moe_gemm_k<1, 256, 128><<<dim3(DMODEL / 128, TOKS / 256, NEXP), 512, 0, stream>>>(
      h, W2t, b2, cnt, offp, list, plist, nullptr, out);
}

// Round 8
// 745.383 us; speedup vs baseline: 1.0166x; 1.0166x over previous
//
#include <hip/hip_runtime.h>
#include <cstdio>
#include <cstdint>

#define TOKS 4096
#define DMODEL 1024
#define DFF 4096
#define NEXP 8
#define NSLOT (2 * TOKS)  // 8192 slots total, exact (top-2 routing)

typedef __bf16 bf16_8 __attribute__((ext_vector_type(8)));
typedef float f32x4 __attribute__((ext_vector_type(4)));
typedef unsigned short u16x8 __attribute__((ext_vector_type(8)));
typedef __attribute__((address_space(1))) const void* gptr_t;
typedef __attribute__((address_space(3))) void* lptr_t;

__device__ __forceinline__ unsigned short f2bf(float f) {
  unsigned int u = __builtin_bit_cast(unsigned int, f);
  u += 0x7FFFu + ((u >> 16) & 1u);
  return (unsigned short)(u >> 16);
}

// ---- transpose + cast fp32 [R][C] -> bf16 k-panels [C/64][R/64][64 n][64 k], per expert ----
// block = 64 k-rows x 256 n-cols: reads 1KB-contiguous chunks, writes 4 x 8KB sequential panels.
__global__ __launch_bounds__(256) void transpose_pack_k(const float* __restrict__ in,
                                                        unsigned short* __restrict__ out,
                                                        int R, int C) {
  __shared__ unsigned short tile[64][258];  // [k][n], pad 2 shorts
  const int e = blockIdx.z;
  const float* inm = in + (size_t)e * R * C;
  unsigned short* outm = out + (size_t)e * R * C;
  const int c0 = blockIdx.x * 256, r0 = blockIdx.y * 64;
  const int tid = threadIdx.x;
#pragma unroll
  for (int i = 0; i < 16; ++i) {
    int idx = i * 256 + tid;
    int r = idx >> 6, c4 = idx & 63;  // 64 float4 per row = 256 cols
    float4 f = *(const float4*)&inm[(size_t)(r0 + r) * C + c0 + c4 * 4];
    tile[r][c4 * 4 + 0] = f2bf(f.x);
    tile[r][c4 * 4 + 1] = f2bf(f.y);
    tile[r][c4 * 4 + 2] = f2bf(f.z);
    tile[r][c4 * 4 + 3] = f2bf(f.w);
  }
  __syncthreads();
  const int kp = r0 >> 6, KP = R >> 6;
#pragma unroll
  for (int i = 0; i < 8; ++i) {
    int ip = i >> 1;                 // which of 4 panels
    int j = (i & 1) * 256 + tid;     // 16B-chunk index within panel (0..511)
    int nl = j >> 3, k0 = (j & 7) * 8;
    u16x8 v;
#pragma unroll
    for (int jj = 0; jj < 8; ++jj) v[jj] = tile[k0 + jj][ip * 64 + nl];
    *(u16x8*)(outm + ((size_t)((c0 >> 6) + ip) * KP + kp) * 4096 + nl * 64 + k0) = v;
  }
}

// ---------------- router: logits -> top2 -> probs -> expert lists ----------------
__global__ __launch_bounds__(256) void router_k(const float* __restrict__ x,
                                                const float* __restrict__ Wr,
                                                const float* __restrict__ br,
                                                int* __restrict__ cnt,
                                                int* __restrict__ list,
                                                float* __restrict__ plist) {
  int t = blockIdx.x * 4 + (threadIdx.x >> 6);
  int lane = threadIdx.x & 63;
  float a[NEXP];
#pragma unroll
  for (int e = 0; e < NEXP; ++e) a[e] = 0.f;
  const float* xr = x + (size_t)t * DMODEL;
  for (int i = lane; i < DMODEL; i += 64) {
    float xv = xr[i];
    const float* wr = Wr + (size_t)i * NEXP;
#pragma unroll
    for (int e = 0; e < NEXP; ++e) a[e] += xv * wr[e];
  }
#pragma unroll
  for (int off = 32; off > 0; off >>= 1) {
#pragma unroll
    for (int e = 0; e < NEXP; ++e) a[e] += __shfl_xor(a[e], off);
  }
  if (lane == 0) {
#pragma unroll
    for (int e = 0; e < NEXP; ++e) a[e] += br[e];
    int i0 = 0; float m0 = a[0];
#pragma unroll
    for (int e = 1; e < NEXP; ++e) if (a[e] > m0) { m0 = a[e]; i0 = e; }
    int i1 = -1; float m1 = -1e30f;
#pragma unroll
    for (int e = 0; e < NEXP; ++e) if (e != i0 && a[e] > m1) { m1 = a[e]; i1 = e; }
    float tt = expf(m1 - m0);
    float p0 = 1.f / (1.f + tt);
    float p1 = 1.f - p0;
    int pos0 = atomicAdd(&cnt[i0], 1);
    list[i0 * TOKS + pos0] = t; plist[i0 * TOKS + pos0] = p0;
    int pos1 = atomicAdd(&cnt[i1], 1);
    list[i1 * TOKS + pos1] = t; plist[i1 * TOKS + pos1] = p1;
  }
}

__global__ void offsets_k(const int* __restrict__ cnt, int* __restrict__ off) {
  if (threadIdx.x == 0) {
    int s = 0;
    for (int e = 0; e < NEXP; ++e) { off[e] = s; s += cnt[e]; }
    off[NEXP] = s;
  }
}

// ---- gather routed x rows -> bf16 k-panels Ap[NSLOT/64][DMODEL/64][64 slot][64 k] ----
__global__ __launch_bounds__(256) void gather_pack_k(const float* __restrict__ x,
                                                     const int* __restrict__ offp,
                                                     const int* __restrict__ list,
                                                     unsigned short* __restrict__ Ap) {
  __shared__ int soff[NEXP + 1];
  __shared__ int stok[64];
  const int sp = blockIdx.x, kp = blockIdx.y;
  const int tid = threadIdx.x;
  if (tid < NEXP + 1) soff[tid] = offp[tid];
  __syncthreads();
  if (tid < 64) {
    int s = sp * 64 + tid;
    int e = 0;
    while (e < NEXP - 1 && s >= soff[e + 1]) ++e;
    stok[tid] = list[e * TOKS + (s - soff[e])];
  }
  __syncthreads();
#pragma unroll
  for (int i = 0; i < 2; ++i) {
    int j = i * 256 + tid;
    int nl = j >> 3, g = j & 7;
    const float* src = x + (size_t)stok[nl] * DMODEL + kp * 64 + g * 8;
    float4 f0 = *(const float4*)src;
    float4 f1 = *(const float4*)(src + 4);
    u16x8 v;
    v[0] = f2bf(f0.x); v[1] = f2bf(f0.y); v[2] = f2bf(f0.z); v[3] = f2bf(f0.w);
    v[4] = f2bf(f1.x); v[5] = f2bf(f1.y); v[6] = f2bf(f1.z); v[7] = f2bf(f1.w);
    *(u16x8*)&Ap[((size_t)sp * (DMODEL / 64) + kp) * 4096 + nl * 64 + g * 8] = v;
  }
}

// ---------------- grouped GEMM on k-panel operands, BM=256, 8 waves, BK=64 ----------------
// All operands in [panel][64 n][64 k] layout -> every staging round = one sequential 8KB burst.
// 2-phase double-buffered pipeline + bijective XCD-chunked swizzle (one expert per XCD).
// MODE 0: A = Ap slots [K=1024], B = W1t panels, out: h panels = relu(.+b1) bf16
// MODE 1: A = h panels [K=4096], B = W2t panels, out: atomicAdd p*(.+b2) into fp32 out
template <int MODE, int BM, int BN>
__global__ __launch_bounds__(512, 2) void moe_gemm_k(
    const unsigned short* __restrict__ Abase, const unsigned short* __restrict__ Bbase,
    const float* __restrict__ bias, const int* __restrict__ cnt, const int* __restrict__ off,
    const int* __restrict__ list, const float* __restrict__ plist,
    unsigned short* __restrict__ Hout, float* __restrict__ Out) {
  constexpr int K  = (MODE == 0) ? DMODEL : DFF;
  constexpr int NN = (MODE == 0) ? DFF : DMODEL;
  constexpr int KP = K >> 6;            // k-panels per n-row-group
  constexpr int NT = NN / BN;
  constexpr int MT = NSLOT / BM;        // 32: covers worst-case per-expert count
  constexpr int NWG = NEXP * MT * NT;
  constexpr int CHUNK = NWG / 8;
  constexpr int WMSZ = BM / 2;
  constexpr int WNSZ = BN / 4;
  constexpr int FM = WMSZ / 16;
  constexpr int FN = WNSZ / 16;
  constexpr int RA = BM / 64;           // A panels staged per step
  constexpr int RB = BN / 64;           // B panels staged per step

  const int flat = blockIdx.x + NT * (blockIdx.y + MT * blockIdx.z);
  const int u = (flat & 7) * CHUNK + (flat >> 3);
  const int nt = u % NT;
  const int mt = (u / NT) % MT;
  const int e = u / (NT * MT);

  const int ce = cnt[e];
  const int m0 = mt * BM;
  if (m0 >= ce) return;
  const int rem = ce - m0;
  const int n0 = nt * BN;
  const int oe = off[e];

  __shared__ unsigned short As[2][BM * 64];
  __shared__ unsigned short Bs[2][BN * 64];

  const int tid = threadIdx.x;
  const int lane = tid & 63;
  const int w = tid >> 6;
  const int wm = w >> 2, wn = w & 3;

  const unsigned short* Bm = Bbase + (size_t)e * NN * K;
  // staging: thread's logical LDS row = c*64 + (tid>>3); source k-group pre-XOR'd
  const int g = (tid & 7) ^ ((tid >> 3) & 7);

  size_t a_src[RA], b_src[RB];
#pragma unroll
  for (int c = 0; c < RA; ++c) {
    int row = c * 64 + (tid >> 3);
    int rr = row < rem ? row : 0;       // clamp padding rows to a valid slot
    size_t arow = (size_t)(oe + m0 + rr);
    a_src[c] = (arow >> 6) * ((size_t)KP * 4096) + (arow & 63) * 64 + g * 8;
  }
#pragma unroll
  for (int c = 0; c < RB; ++c)
    b_src[c] = ((size_t)((n0 >> 6) + c) * KP) * 4096 + (tid >> 3) * 64 + g * 8;

  f32x4 acc[FM][FN];
#pragma unroll
  for (int i = 0; i < FM; ++i)
#pragma unroll
    for (int j = 0; j < FN; ++j) acc[i][j] = (f32x4){0.f, 0.f, 0.f, 0.f};

  auto STAGE = [&](int buf, int t) {
    const size_t ko = (size_t)t * 4096;  // next k-panel
#pragma unroll
    for (int c = 0; c < RA; ++c)
      __builtin_amdgcn_global_load_lds((gptr_t)(Abase + a_src[c] + ko),
                                       (lptr_t)&As[buf][(c * 512 + tid) * 8], 16, 0, 0);
#pragma unroll
    for (int c = 0; c < RB; ++c)
      __builtin_amdgcn_global_load_lds((gptr_t)(Bm + b_src[c] + ko),
                                       (lptr_t)&Bs[buf][(c * 512 + tid) * 8], 16, 0, 0);
  };

  auto COMPUTE = [&](int buf) {
#pragma unroll
    for (int kk = 0; kk < 2; ++kk) {
      bf16_8 av[FM], bv[FN];
#pragma unroll
      for (int fm = 0; fm < FM; ++fm) {
        int row = wm * WMSZ + fm * 16 + (lane & 15);
        int slot = row * 8 + ((kk * 4 + (lane >> 4)) ^ (row & 7));
        av[fm] = *(const bf16_8*)&As[buf][slot * 8];
      }
#pragma unroll
      for (int fc = 0; fc < FN; ++fc) {
        int row = wn * WNSZ + fc * 16 + (lane & 15);
        int slot = row * 8 + ((kk * 4 + (lane >> 4)) ^ (row & 7));
        bv[fc] = *(const bf16_8*)&Bs[buf][slot * 8];
      }
#pragma unroll
      for (int fm = 0; fm < FM; ++fm)
#pragma unroll
        for (int fc = 0; fc < FN; ++fc)
          acc[fm][fc] = __builtin_amdgcn_mfma_f32_16x16x32_bf16(av[fm], bv[fc],
                                                                acc[fm][fc], 0, 0, 0);
    }
  };

  constexpr int NSTEP = K / 64;
  STAGE(0, 0);
  __syncthreads();
  int cur = 0;
  for (int t = 0; t < NSTEP - 1; ++t) {
    STAGE(cur ^ 1, t + 1);
    COMPUTE(cur);
    __syncthreads();
    cur ^= 1;
  }
  COMPUTE(cur);

  const float* be = bias + (size_t)e * NN + n0;
  if (MODE == 0) {
#pragma unroll
    for (int fm = 0; fm < FM; ++fm) {
#pragma unroll
      for (int j = 0; j < 4; ++j) {
        int row = wm * WMSZ + fm * 16 + (lane >> 4) * 4 + j;
        if (row < rem) {
          size_t s = (size_t)(oe + m0 + row);
          size_t pb = (s >> 6) * ((size_t)(DFF >> 6) * 4096) + (s & 63) * 64;
#pragma unroll
          for (int fc = 0; fc < FN; ++fc) {
            int col = wn * WNSZ + fc * 16 + (lane & 15);
            float v = acc[fm][fc][j] + be[col];
            int gc = n0 + col;
            Hout[pb + (size_t)(gc >> 6) * 4096 + (gc & 63)] = f2bf(fmaxf(v, 0.f));
          }
        }
      }
    }
  } else {
#pragma unroll
    for (int fm = 0; fm < FM; ++fm) {
#pragma unroll
      for (int j = 0; j < 4; ++j) {
        int row = wm * WMSZ + fm * 16 + (lane >> 4) * 4 + j;
        if (row < rem) {
          int tok = list[e * TOKS + m0 + row];
          float p = plist[e * TOKS + m0 + row];
          float* orow = Out + (size_t)tok * DMODEL + n0;
#pragma unroll
          for (int fc = 0; fc < FN; ++fc) {
            int col = wn * WNSZ + fc * 16 + (lane & 15);
            atomicAdd(&orow[col], p * (acc[fm][fc][j] + be[col]));
          }
        }
      }
    }
  }
}

extern "C" void kernel_launch(void* const* d_in, const int* in_sizes, int n_in,
                              void* d_out, int out_size, void* d_ws, size_t ws_size,
                              hipStream_t stream) {
  const float* x  = (const float*)d_in[0];
  const float* Wr = (const float*)d_in[1];
  const float* br = (const float*)d_in[2];
  const float* W1 = (const float*)d_in[3];
  const float* b1 = (const float*)d_in[4];
  const float* W2 = (const float*)d_in[5];
  const float* b2 = (const float*)d_in[6];
  float* out = (float*)d_out;

  const size_t SZ_W = (size_t)NEXP * DMODEL * DFF;
  char* ws = (char*)d_ws;
  size_t o = 0;
  unsigned short* W1t = (unsigned short*)(ws + o); o += SZ_W * 2;                    // panels
  unsigned short* W2t = (unsigned short*)(ws + o); o += SZ_W * 2;                    // panels
  unsigned short* Ap  = (unsigned short*)(ws + o); o += (size_t)NSLOT * DMODEL * 2;  // panels
  unsigned short* h   = (unsigned short*)(ws + o); o += (size_t)NSLOT * DFF * 2;     // panels
  int*   cnt   = (int*)(ws + o);   o += 256;
  int*   offp  = (int*)(ws + o);   o += 256;
  int*   list  = (int*)(ws + o);   o += (size_t)NEXP * TOKS * 4;
  float* plist = (float*)(ws + o); o += (size_t)NEXP * TOKS * 4;
  if (o > ws_size) {
    fprintf(stderr, "kernel_launch: ws too small: need %zu have %zu\n", o, ws_size);
    hipMemsetAsync(d_out, 0, (size_t)out_size * 4, stream);
    return;
  }

  hipMemsetAsync(cnt, 0, 256, stream);
  hipMemsetAsync(d_out, 0, (size_t)out_size * 4, stream);

  transpose_pack_k<<<dim3(DFF / 256, DMODEL / 64, NEXP), 256, 0, stream>>>(W1, W1t, DMODEL, DFF);
  transpose_pack_k<<<dim3(DMODEL / 256, DFF / 64, NEXP), 256, 0, stream>>>(W2, W2t, DFF, DMODEL);
  router_k<<<TOKS / 4, 256, 0, stream>>>(x, Wr, br, cnt, list, plist);
  offsets_k<<<1, 64, 0, stream>>>(cnt, offp);
  gather_pack_k<<<dim3(NSLOT / 64, DMODEL / 64), 256, 0, stream>>>(x, offp, list, Ap);
  moe_gemm_k<0, 256, 256><<<dim3(DFF / 256, NSLOT / 256, NEXP), 512, 0, stream>>>(
      Ap, W1t, b1, cnt, offp, list, plist, h, nullptr);
  moe_gemm_k<1, 256, 128><<<dim3(DMODEL / 128, NSLOT / 256, NEXP), 512, 0, stream>>>(
      h, W2t, b2, cnt, offp, list, plist, nullptr, out);
}